// Round 2
// baseline (73.794 us; speedup 1.0000x reference)
//
#include <hip/hip_runtime.h>
#include <math.h>

// Tropical min-max matmul: out[b,o] = min_i max(x[b,i], w[i,o])
// B=1024, I=512, O=512, fp32.
//
// Round 17: threshold-compaction scan (replaces Round 16's bitonic sort
// + voted early-exit, both suspects for the ~31us kernel residual).
//  - Exact certificate, no sort: S = {i : x_i <= tau}, tau = xmin +
//    0.25*(xmax-xmin). acc = min_{i in S} max(x_i, w_io). If acc <= tau
//    the unscanned i (x_i > tau >= acc) cannot lower the min: exact.
//    P(column fails certificate) ~ 0.75^128 ~ 1e-14; brute fallback
//    kept for arbitrary inputs (exactness), never taken on this data.
//  - Compaction: ballot + popc prefix, 3 barriers total (vs 45).
//  - Scan: block-UNIFORM trip count (|S| padded to 8), no votes, no
//    divergent exits; ping-pong 2-chunk prefetch; wave = 128 cols,
//    2 cols/lane; w-row gathers are wave-uniform rows -> 512B
//    contiguous per wave, L2-resident.
//  - 1024 blocks x 256 thr = 4 blocks/CU (whole grid resident).

__global__ __launch_bounds__(256, 4) void minmax_tau(
    const float* __restrict__ x,    // [1024, 512]
    const float* __restrict__ w,    // [512, 512]
    float* __restrict__ out)        // [1024, 512]
{
    __shared__ __align__(16) float sv[528];   // compacted x values (+pad)
    __shared__ __align__(16) int   si[528];   // compacted indices
    __shared__ __align__(16) float xraw[512]; // raw row (fallback only)
    __shared__ float red[8];                  // per-wave min/max
    __shared__ int   cnt[4];                  // per-wave compact counts

    const int t    = threadIdx.x;   // 0..255
    const int b    = blockIdx.x;    // row
    const int wid  = t >> 6;
    const int lane = t & 63;

    // ---- load row, stash raw copy ----
    const float2 v = *(const float2*)(x + (size_t)b * 512 + t * 2);
    *(float2*)(&xraw[t * 2]) = v;

    // ---- row min/max: wave shuffle reduce, then 4-way LDS combine ----
    float mn = fminf(v.x, v.y), mx = fmaxf(v.x, v.y);
#pragma unroll
    for (int d = 32; d; d >>= 1) {
        mn = fminf(mn, __shfl_xor(mn, d));
        mx = fmaxf(mx, __shfl_xor(mx, d));
    }
    if (lane == 0) { red[wid] = mn; red[4 + wid] = mx; }
    __syncthreads();

    const float xmin = fminf(fminf(red[0], red[1]), fminf(red[2], red[3]));
    const float xmax = fmaxf(fmaxf(red[4], red[5]), fmaxf(red[6], red[7]));
    const float tau  = xmin + 0.25f * (xmax - xmin);

    // ---- compact (val, idx) with val <= tau: ballot + prefix ----
    const bool p0 = (v.x <= tau);
    const bool p1 = (v.y <= tau);
    const unsigned long long m0 = __ballot(p0);
    const unsigned long long m1 = __ballot(p1);
    const int c0 = __popcll(m0);
    const int c1 = __popcll(m1);
    if (lane == 0) cnt[wid] = c0 + c1;
    __syncthreads();

    int base = 0;
#pragma unroll
    for (int u = 0; u < 4; ++u) base += (u < wid) ? cnt[u] : 0;
    const unsigned long long below = (1ull << lane) - 1ull;
    if (p0) { const int q = base + __popcll(m0 & below);      sv[q] = v.x; si[q] = t * 2; }
    if (p1) { const int q = base + c0 + __popcll(m1 & below); sv[q] = v.y; si[q] = t * 2 + 1; }

    const int E  = cnt[0] + cnt[1] + cnt[2] + cnt[3];   // >=1 (xmin in S)
    const int Ep = (E + 7) & ~7;                        // multiple of 8
    if (t < Ep - E) { sv[E + t] = INFINITY; si[E + t] = 0; }  // harmless pad
    __syncthreads();

    // ---- uniform scan over compacted list: 2 cols/lane ----
    const int o = wid * 128 + lane * 2;
    const float* wp = w + o;
    float2 acc = make_float2(INFINITY, INFINITY);

#define LDCHUNK(J, XS, R0, R1, R2, R3) do {                     \
        XS = *(const float4*)(&sv[(J)]);                        \
        const int4 ix_ = *(const int4*)(&si[(J)]);              \
        R0 = *(const float2*)(wp + (ix_.x << 9));               \
        R1 = *(const float2*)(wp + (ix_.y << 9));               \
        R2 = *(const float2*)(wp + (ix_.z << 9));               \
        R3 = *(const float2*)(wp + (ix_.w << 9));               \
    } while (0)

#define PROCESS(XS, R0, R1, R2, R3) do {                        \
        const float t0 = fmaxf(XS.x, R0.x);                     \
        const float t1 = fmaxf(XS.y, R1.x);                     \
        const float t2 = fmaxf(XS.z, R2.x);                     \
        const float t3 = fmaxf(XS.w, R3.x);                     \
        acc.x = fminf(fminf(acc.x, t0), t1);  /* v_min3 */      \
        acc.x = fminf(fminf(acc.x, t2), t3);                    \
        const float u0 = fmaxf(XS.x, R0.y);                     \
        const float u1 = fmaxf(XS.y, R1.y);                     \
        const float u2 = fmaxf(XS.z, R2.y);                     \
        const float u3 = fmaxf(XS.w, R3.y);                     \
        acc.y = fminf(fminf(acc.y, u0), u1);                    \
        acc.y = fminf(fminf(acc.y, u2), u3);                    \
    } while (0)

    {
        const int halfs = Ep >> 3;          // pairs of 4-element chunks
        float4 xsA, xsB;
        float2 a0, a1, a2, a3, b0, b1, b2, b3;
        LDCHUNK(0, xsA, a0, a1, a2, a3);
        LDCHUNK(4, xsB, b0, b1, b2, b3);
        for (int p = 0; p < halfs; ++p) {
            PROCESS(xsA, a0, a1, a2, a3);
            if (p + 1 < halfs) LDCHUNK(8 * p + 8,  xsA, a0, a1, a2, a3);
            PROCESS(xsB, b0, b1, b2, b3);
            if (p + 1 < halfs) LDCHUNK(8 * p + 12, xsB, b0, b1, b2, b3);
        }
    }

    // ---- certificate; exact fallback (never taken for uniform data) ----
    if (!__all((acc.x <= tau) && (acc.y <= tau))) {
        for (int i = 0; i < 512; i += 4) {
            const float4 xs = *(const float4*)(&xraw[i]);
            float2 r0 = *(const float2*)(wp + ((i + 0) << 9));
            float2 r1 = *(const float2*)(wp + ((i + 1) << 9));
            float2 r2 = *(const float2*)(wp + ((i + 2) << 9));
            float2 r3 = *(const float2*)(wp + ((i + 3) << 9));
            PROCESS(xs, r0, r1, r2, r3);
        }
    }

#undef LDCHUNK
#undef PROCESS

    *(float2*)(out + (size_t)b * 512 + o) = acc;
}

extern "C" void kernel_launch(void* const* d_in, const int* in_sizes, int n_in,
                              void* d_out, int out_size, void* d_ws, size_t ws_size,
                              hipStream_t stream) {
    const float* x = (const float*)d_in[0];   // [1024, 512]
    const float* w = (const float*)d_in[1];   // [512, 512]
    float* out = (float*)d_out;               // [1024, 512]

    minmax_tau<<<dim3(1024), 256, 0, stream>>>(x, w, out);
}

// Round 3
// 70.965 us; speedup vs baseline: 1.0399x; 1.0399x over previous
//
#include <hip/hip_runtime.h>
#include <math.h>

// Tropical min-max matmul: out[b,o] = min_i max(x[b,i], w[i,o])
// B=1024, I=512, O=512, fp32.
//
// Round 18 = Round 17 with two shrinks of the residual kernel cost:
//  1) Staged certificate: scan S1={x<=tau1}, tau1=xmin+0.125r (~64 els,
//     half of R17); per-wave vote; only failing waves (~5%) escalate to
//     the (tau1,tau2=0.25r] bucket; full-512 fallback only if tau2
//     certificate fails (P~1e-14 on this data; kept for exactness).
//  2) 4 cols/lane (float4 w-gathers, 1KB/wave-inst) with 128-thread
//     blocks: half the VMEM instructions per update, one float4 acc.
//     1024 blocks x 128 thr = 8 blocks/CU (whole grid resident,
//     16 waves/CU).
//  Exactness: after scanning all i with x_i <= tau, if acc[o] <= tau
//  then any unscanned i has max(x_i,w) >= x_i > tau >= acc: exact.
//  Fallback rescans everything (idempotent under min).

__global__ __launch_bounds__(128, 4) void minmax_tau2(
    const float* __restrict__ x,    // [1024, 512]
    const float* __restrict__ w,    // [512, 512]
    float* __restrict__ out)        // [1024, 512]
{
    __shared__ __align__(16) float sv[520];   // compacted x values (+pad)
    __shared__ __align__(16) int   si[520];   // compacted indices
    __shared__ float red[4];                  // per-wave min/max
    __shared__ int   cnt[4];                  // per-wave {lo,hi} counts

    const int t    = threadIdx.x;   // 0..127
    const int b    = blockIdx.x;    // row
    const int wid  = t >> 6;        // 0..1
    const int lane = t & 63;

    // ---- load row: 4 elements/lane ----
    const float4 v = *(const float4*)(x + (size_t)b * 512 + t * 4);

    // ---- row min/max: wave shuffle reduce, 2-wave LDS combine ----
    float mn = fminf(fminf(v.x, v.y), fminf(v.z, v.w));
    float mx = fmaxf(fmaxf(v.x, v.y), fmaxf(v.z, v.w));
#pragma unroll
    for (int d = 32; d; d >>= 1) {
        mn = fminf(mn, __shfl_xor(mn, d));
        mx = fmaxf(mx, __shfl_xor(mx, d));
    }
    if (lane == 0) { red[wid] = mn; red[2 + wid] = mx; }
    __syncthreads();

    const float xmin = fminf(red[0], red[1]);
    const float xmax = fmaxf(red[2], red[3]);
    const float r    = xmax - xmin;
    const float tau1 = xmin + 0.125f * r;
    const float tau2 = xmin + 0.25f  * r;

    // ---- two-class compaction: lo = (x<=tau1), hi = (tau1<x<=tau2) ----
    const bool l0 = (v.x <= tau1), l1 = (v.y <= tau1),
               l2 = (v.z <= tau1), l3 = (v.w <= tau1);
    const bool h0 = (v.x <= tau2) && !l0, h1 = (v.y <= tau2) && !l1,
               h2 = (v.z <= tau2) && !l2, h3 = (v.w <= tau2) && !l3;
    const unsigned long long L0 = __ballot(l0), L1 = __ballot(l1),
                             L2 = __ballot(l2), L3 = __ballot(l3);
    const unsigned long long H0 = __ballot(h0), H1 = __ballot(h1),
                             H2 = __ballot(h2), H3 = __ballot(h3);
    const int cLo = __popcll(L0) + __popcll(L1) + __popcll(L2) + __popcll(L3);
    const int cHi = __popcll(H0) + __popcll(H1) + __popcll(H2) + __popcll(H3);
    if (lane == 0) { cnt[wid] = cLo; cnt[2 + wid] = cHi; }
    __syncthreads();

    const int E1   = cnt[0] + cnt[1];
    const int Ep1  = (E1 + 7) & ~7;
    const int E2e  = Ep1 + cnt[2] + cnt[3];
    const int Ep2  = (E2e + 7) & ~7;
    const int loB  = (wid == 0) ? 0 : cnt[0];
    const int hiB  = Ep1 + ((wid == 0) ? 0 : cnt[2]);

    {   // scatter this lane's elements (sequential slot order)
        const unsigned long long below = (1ull << lane) - 1ull;
        const int i0 = t * 4;
        int q = loB + __popcll(L0 & below);
        int p = hiB + __popcll(H0 & below);
        if (l0) { sv[q] = v.x; si[q] = i0; }
        if (h0) { sv[p] = v.x; si[p] = i0; }
        q = loB + __popcll(L0) + __popcll(L1 & below);
        p = hiB + __popcll(H0) + __popcll(H1 & below);
        if (l1) { sv[q] = v.y; si[q] = i0 + 1; }
        if (h1) { sv[p] = v.y; si[p] = i0 + 1; }
        q = loB + __popcll(L0) + __popcll(L1) + __popcll(L2 & below);
        p = hiB + __popcll(H0) + __popcll(H1) + __popcll(H2 & below);
        if (l2) { sv[q] = v.z; si[q] = i0 + 2; }
        if (h2) { sv[p] = v.z; si[p] = i0 + 2; }
        q = loB + __popcll(L0) + __popcll(L1) + __popcll(L2) + __popcll(L3 & below);
        p = hiB + __popcll(H0) + __popcll(H1) + __popcll(H2) + __popcll(H3 & below);
        if (l3) { sv[q] = v.w; si[q] = i0 + 3; }
        if (h3) { sv[p] = v.w; si[p] = i0 + 3; }
    }
    if (t < Ep1 - E1)  { sv[E1 + t]  = INFINITY; si[E1 + t]  = 0; }
    if (t < Ep2 - E2e) { sv[E2e + t] = INFINITY; si[E2e + t] = 0; }
    __syncthreads();

    // ---- uniform scan: 4 cols/lane, float4 gathers ----
    const int o = wid * 256 + lane * 4;
    const float* wp = w + o;
    float4 acc = make_float4(INFINITY, INFINITY, INFINITY, INFINITY);

#define LDCHUNK(J, XS, R0, R1, R2, R3) do {                     \
        XS = *(const float4*)(&sv[(J)]);                        \
        const int4 ix_ = *(const int4*)(&si[(J)]);              \
        R0 = *(const float4*)(wp + ((size_t)ix_.x << 9));       \
        R1 = *(const float4*)(wp + ((size_t)ix_.y << 9));       \
        R2 = *(const float4*)(wp + ((size_t)ix_.z << 9));       \
        R3 = *(const float4*)(wp + ((size_t)ix_.w << 9));       \
    } while (0)

#define PROCESS(XS, R0, R1, R2, R3) do {                                      \
        const float4 t0 = make_float4(fmaxf(XS.x, R0.x), fmaxf(XS.x, R0.y),   \
                                      fmaxf(XS.x, R0.z), fmaxf(XS.x, R0.w)); \
        const float4 t1 = make_float4(fmaxf(XS.y, R1.x), fmaxf(XS.y, R1.y),   \
                                      fmaxf(XS.y, R1.z), fmaxf(XS.y, R1.w)); \
        const float4 t2 = make_float4(fmaxf(XS.z, R2.x), fmaxf(XS.z, R2.y),   \
                                      fmaxf(XS.z, R2.z), fmaxf(XS.z, R2.w)); \
        const float4 t3 = make_float4(fmaxf(XS.w, R3.x), fmaxf(XS.w, R3.y),   \
                                      fmaxf(XS.w, R3.z), fmaxf(XS.w, R3.w)); \
        acc.x = fminf(fminf(acc.x, t0.x), t1.x);  /* v_min3 */                \
        acc.x = fminf(fminf(acc.x, t2.x), t3.x);                              \
        acc.y = fminf(fminf(acc.y, t0.y), t1.y);                              \
        acc.y = fminf(fminf(acc.y, t2.y), t3.y);                              \
        acc.z = fminf(fminf(acc.z, t0.z), t1.z);                              \
        acc.z = fminf(fminf(acc.z, t2.z), t3.z);                              \
        acc.w = fminf(fminf(acc.w, t0.w), t1.w);                              \
        acc.w = fminf(fminf(acc.w, t2.w), t3.w);                              \
    } while (0)

    auto scan = [&](const int base, const int nh) {
        if (nh <= 0) return;
        float4 xsA, xsB;
        float4 a0, a1, a2, a3, b0, b1, b2, b3;
        LDCHUNK(base,     xsA, a0, a1, a2, a3);
        LDCHUNK(base + 4, xsB, b0, b1, b2, b3);
        for (int p = 0; p < nh; ++p) {
            PROCESS(xsA, a0, a1, a2, a3);
            if (p + 1 < nh) LDCHUNK(base + 8 * p + 8,  xsA, a0, a1, a2, a3);
            PROCESS(xsB, b0, b1, b2, b3);
            if (p + 1 < nh) LDCHUNK(base + 8 * p + 12, xsB, b0, b1, b2, b3);
        }
    };

    // stage 1: x <= tau1
    scan(0, Ep1 >> 3);
    const float amx1 = fmaxf(fmaxf(acc.x, acc.y), fmaxf(acc.z, acc.w));
    if (!__all(amx1 <= tau1)) {
        // stage 2: tau1 < x <= tau2  (~5% of waves)
        scan(Ep1, (Ep2 - Ep1) >> 3);
        const float amx2 = fmaxf(fmaxf(acc.x, acc.y), fmaxf(acc.z, acc.w));
        if (!__all(amx2 <= tau2)) {
            // exact fallback: rescan everything (P ~ 1e-14 here)
            const float* xrow = x + (size_t)b * 512;
            for (int i = 0; i < 512; i += 4) {
                const float4 xs = *(const float4*)(xrow + i);
                const float4 r0 = *(const float4*)(wp + ((size_t)(i + 0) << 9));
                const float4 r1 = *(const float4*)(wp + ((size_t)(i + 1) << 9));
                const float4 r2 = *(const float4*)(wp + ((size_t)(i + 2) << 9));
                const float4 r3 = *(const float4*)(wp + ((size_t)(i + 3) << 9));
                PROCESS(xs, r0, r1, r2, r3);
            }
        }
    }

#undef LDCHUNK
#undef PROCESS

    *(float4*)(out + (size_t)b * 512 + o) = acc;
}

extern "C" void kernel_launch(void* const* d_in, const int* in_sizes, int n_in,
                              void* d_out, int out_size, void* d_ws, size_t ws_size,
                              hipStream_t stream) {
    const float* x = (const float*)d_in[0];   // [1024, 512]
    const float* w = (const float*)d_in[1];   // [512, 512]
    float* out = (float*)d_out;               // [1024, 512]

    minmax_tau2<<<dim3(1024), 128, 0, stream>>>(x, w, out);
}